// Round 3
// baseline (119.477 us; speedup 1.0000x reference)
//
#include <hip/hip_runtime.h>
#include <math.h>

// Problem constants (from reference): B=1024, C=256, H=W=24
static constexpr int B_N  = 1024;
static constexpr int C_N  = 256;
static constexpr int HW_N = 576;           // 24*24, = 144 float4
static constexpr float TEMP_INV = 1.0f / 0.07f;

typedef __attribute__((ext_vector_type(8))) short bf16x8;
typedef __attribute__((ext_vector_type(4))) float f32x4;

// float -> bf16 round-to-nearest-even (inputs are finite; no NaN handling needed)
static __device__ __forceinline__ unsigned short f2bf(float f) {
    unsigned u = __float_as_uint(f);
    return (unsigned short)((u + 0x7FFFu + ((u >> 16) & 1u)) >> 16);
}

// ---------------------------------------------------------------------------
// Kernel A (fused): global-average-pool + L2-normalize + bf16 cast.
//  Blocks 0..1023  : one block per image b. 16 waves; wave w averages channels
//                    [w*16, w*16+16) (576 contiguous floats each, coalesced
//                    float4 reads), writes means to LDS; wave 0 then computes
//                    the row norm and stores the normalized bf16 row to Ab.
//  Blocks 1024..1039: text rows. Each wave normalizes 4 rows (one float4 per
//                    lane per row) and stores bf16 to Bb.
// Block 0 also zeroes the loss accumulator + ticket (used one launch later).
// ---------------------------------------------------------------------------
__global__ __launch_bounds__(1024) void fused_prep_kernel(const float* __restrict__ img,
                                                          const float* __restrict__ text,
                                                          unsigned short* __restrict__ Ab,
                                                          unsigned short* __restrict__ Bb,
                                                          float* __restrict__ loss_acc,
                                                          unsigned int* __restrict__ ticket) {
    __shared__ float means[C_N];
    const int t    = threadIdx.x;
    const int w    = t >> 6;
    const int lane = t & 63;

    if (blockIdx.x == 0 && t == 0) { *loss_acc = 0.0f; *ticket = 0u; }

    if (blockIdx.x < (unsigned)B_N) {
        const int b = blockIdx.x;
        #pragma unroll
        for (int ch = 0; ch < 16; ++ch) {
            const int c = (w << 4) + ch;
            const float4* src = (const float4*)(img + ((size_t)b * C_N + c) * HW_N);
            float s = 0.0f;
            #pragma unroll
            for (int it = 0; it < 3; ++it) {
                const int idx = lane + it * 64;             // 144 float4 per channel
                if (idx < 144) {
                    const float4 v = src[idx];
                    s += (v.x + v.y) + (v.z + v.w);
                }
            }
            #pragma unroll
            for (int off = 32; off > 0; off >>= 1) s += __shfl_xor(s, off, 64);
            if (lane == 0) means[c] = s * (1.0f / (float)HW_N);
        }
        __syncthreads();
        if (w == 0) {
            const float4 v = ((const float4*)means)[lane];
            float ss = v.x * v.x + v.y * v.y + v.z * v.z + v.w * v.w;
            #pragma unroll
            for (int off = 32; off > 0; off >>= 1) ss += __shfl_xor(ss, off, 64);
            const float inv = 1.0f / fmaxf(sqrtf(ss), 1e-12f);   // matches F.normalize
            ushort4 o;
            o.x = f2bf(v.x * inv); o.y = f2bf(v.y * inv);
            o.z = f2bf(v.z * inv); o.w = f2bf(v.w * inv);
            ((ushort4*)(Ab + (size_t)b * C_N))[lane] = o;
        }
    } else {
        const int rb = (blockIdx.x - B_N) * 64;                  // 64 text rows/block
        #pragma unroll
        for (int rr = 0; rr < 4; ++rr) {
            const int r = rb + (w << 2) + rr;
            const float4 v = ((const float4*)(text + (size_t)r * C_N))[lane];
            float ss = v.x * v.x + v.y * v.y + v.z * v.z + v.w * v.w;
            #pragma unroll
            for (int off = 32; off > 0; off >>= 1) ss += __shfl_xor(ss, off, 64);
            const float inv = 1.0f / fmaxf(sqrtf(ss), 1e-12f);
            ushort4 o;
            o.x = f2bf(v.x * inv); o.y = f2bf(v.y * inv);
            o.z = f2bf(v.z * inv); o.w = f2bf(v.w * inv);
            ((ushort4*)(Bb + (size_t)r * C_N))[lane] = o;
        }
    }
}

// ---------------------------------------------------------------------------
// Kernel B: bf16 MFMA GEMM (64x64 tile/block, whole K=256 staged once into
// LDS, XOR-swizzled for conflict-free ds_read_b128 fragment reads) + fused
// BCE-with-logits loss reduction + atomic-ticket finalize (no extra kernel).
// Rows are pre-normalized, so logits = acc / TEMP directly; the loss is
// transpose-invariant (labels equality is symmetric).
// ---------------------------------------------------------------------------
__global__ __launch_bounds__(256) void gemm_loss_kernel(const unsigned short* __restrict__ Ab,
                                                        const unsigned short* __restrict__ Bb,
                                                        const int* __restrict__ labels,
                                                        float* __restrict__ loss_acc,
                                                        unsigned int* __restrict__ ticket,
                                                        float* __restrict__ out) {
    __shared__ unsigned short Abuf[64 * 256];   // 32 KB, swizzled
    __shared__ unsigned short Bbuf[64 * 256];   // 32 KB, swizzled

    const int t = threadIdx.x;
    const int rowBase = (blockIdx.x & 15) << 6;
    const int colBase = (blockIdx.x >> 4) << 6;

    // ---- Stage both 64x256 bf16 tiles (one shot, no k-loop). 16B chunks:
    // chunk c -> (row = c>>5, kc = c&31); LDS byte = (row*512+kc*16) ^ ((row&7)<<4).
    #pragma unroll
    for (int i = 0; i < 8; ++i) {
        const int c   = t + (i << 8);           // 0..2047
        const int row = c >> 5;
        const int kc  = c & 31;
        const unsigned off = (unsigned)((row << 9) + (kc << 4)) ^ (unsigned)((row & 7) << 4);
        uint4 va = ((const uint4*)(Ab + (size_t)(rowBase + row) * C_N))[kc];
        *(uint4*)((char*)Abuf + off) = va;
        uint4 vb = ((const uint4*)(Bb + (size_t)(colBase + row) * C_N))[kc];
        *(uint4*)((char*)Bbuf + off) = vb;
    }
    __syncthreads();

    // ---- MFMA: wave w owns rows [w*16, w*16+16) x all 64 cols.
    const int w    = t >> 6;
    const int lane = t & 63;
    const int m16  = lane & 15;
    const int kg   = lane >> 4;

    f32x4 acc[4] = {{0.f, 0.f, 0.f, 0.f}, {0.f, 0.f, 0.f, 0.f},
                    {0.f, 0.f, 0.f, 0.f}, {0.f, 0.f, 0.f, 0.f}};

    #pragma unroll
    for (int s = 0; s < 8; ++s) {               // K = 256 = 8 * 32
        const int kc   = (s << 2) + kg;         // 16B chunk index along k
        const int arow = (w << 4) + m16;
        const bf16x8 a = *(const bf16x8*)((char*)Abuf +
                            (((unsigned)((arow << 9) + (kc << 4))) ^ (unsigned)((arow & 7) << 4)));
        #pragma unroll
        for (int ct = 0; ct < 4; ++ct) {
            const int brow = (ct << 4) + m16;
            const bf16x8 b = *(const bf16x8*)((char*)Bbuf +
                                (((unsigned)((brow << 9) + (kc << 4))) ^ (unsigned)((brow & 7) << 4)));
            acc[ct] = __builtin_amdgcn_mfma_f32_16x16x32_bf16(a, b, acc[ct], 0, 0, 0);
        }
    }

    // ---- Epilogue: logits -> BCE terms -> block reduction -> ticket finalize.
    // D frag: col = lane&15, row = (lane>>4)*4 + reg  [measured m89/m91]
    float lsum = 0.0f;
    const int gi0 = rowBase + (w << 4) + (kg << 2);
    int labi[4];
    #pragma unroll
    for (int r = 0; r < 4; ++r) labi[r] = labels[gi0 + r];
    #pragma unroll
    for (int ct = 0; ct < 4; ++ct) {
        const int gj = colBase + (ct << 4) + m16;
        const int labj = labels[gj];
        #pragma unroll
        for (int r = 0; r < 4; ++r) {
            const float x = acc[ct][r] * TEMP_INV;
            const float z = (labi[r] == labj) ? 1.0f : 0.0f;
            // softplus via fast hw exp/log (v_exp_f32 / v_log_f32 based)
            const float sp = fmaxf(x, 0.0f) + __logf(1.0f + __expf(-fabsf(x)));
            lsum += sp - x * z;
        }
    }

    #pragma unroll
    for (int off = 32; off > 0; off >>= 1) lsum += __shfl_xor(lsum, off, 64);
    __syncthreads();                             // done reading LDS; reuse for reduce
    float* red = (float*)Abuf;
    if ((t & 63) == 0) red[w] = lsum;
    __syncthreads();
    if (t == 0) {
        const float bsum = red[0] + red[1] + red[2] + red[3];
        atomicAdd(loss_acc, bsum);
        __threadfence();
        const unsigned old = atomicAdd(ticket, 1u);
        if (old == 255u) {                       // last of 256 blocks
            const float total = atomicAdd(loss_acc, 0.0f);  // device-scope read
            out[0] = total * (1.0f / ((float)B_N * (float)B_N));
        }
    }
}

extern "C" void kernel_launch(void* const* d_in, const int* in_sizes, int n_in,
                              void* d_out, int out_size, void* d_ws, size_t ws_size,
                              hipStream_t stream) {
    const float* img    = (const float*)d_in[0];   // [1024,256,24,24] fp32
    const float* text   = (const float*)d_in[1];   // [1024,256] fp32
    const int*   labels = (const int*)d_in[2];     // [1024] int32 (JAX demotes int64)
    float* out = (float*)d_out;

    char* ws = (char*)d_ws;
    unsigned short* Ab       = (unsigned short*)ws;                    // 512 KiB bf16
    unsigned short* Bb       = (unsigned short*)(ws + (512 << 10));    // 512 KiB bf16
    float*          loss_acc = (float*)(ws + (1 << 20));               // 4 B
    unsigned int*   ticket   = (unsigned int*)(ws + (1 << 20) + 4);    // 4 B

    fused_prep_kernel<<<B_N + 16, 1024, 0, stream>>>(img, text, Ab, Bb, loss_acc, ticket);
    gemm_loss_kernel<<<256, 256, 0, stream>>>(Ab, Bb, labels, loss_acc, ticket, out);
}

// Round 4
// 108.706 us; speedup vs baseline: 1.0991x; 1.0991x over previous
//
#include <hip/hip_runtime.h>
#include <math.h>

// Problem constants (from reference): B=1024, C=256, H=W=24
static constexpr int B_N  = 1024;
static constexpr int C_N  = 256;
static constexpr int HW_N = 576;           // floats per channel = 144 float4
static constexpr float TEMP_INV = 1.0f / 0.07f;

typedef __attribute__((ext_vector_type(8))) short bf16x8;
typedef __attribute__((ext_vector_type(4))) float f32x4;
typedef __attribute__((ext_vector_type(4))) float f4v;

// float -> bf16 round-to-nearest-even (inputs are finite; no NaN handling needed)
static __device__ __forceinline__ unsigned short f2bf(float f) {
    unsigned u = __float_as_uint(f);
    return (unsigned short)((u + 0x7FFFu + ((u >> 16) & 1u)) >> 16);
}

// ---------------------------------------------------------------------------
// Kernel A: pool v2 + concurrent text normalize.
//  Blocks 0..31    : text rows (32 rows/block, 8 per wave): L2-normalize +
//                    bf16 cast -> Bb. Independent of img; runs under the
//                    HBM-bound pooling phase for free. Block 0 zeroes acc.
//  Blocks 32..16415: pooling. Each wave owns 4 channels = 576 float4.
//                    9 dense nontemporal loads/lane issued before any use
//                    (MLP: 9 loads in flight/wave vs 3 before), select-
//                    accumulate into 4 channel partials, 4 interleaved
//                    butterfly reductions, lane 0 writes float4 of means.
// ---------------------------------------------------------------------------
__global__ __launch_bounds__(256) void pool_kernel(const float* __restrict__ img,
                                                   const float* __restrict__ text,
                                                   float* __restrict__ pooled,
                                                   unsigned short* __restrict__ Bb,
                                                   float* __restrict__ loss_acc,
                                                   unsigned int* __restrict__ ticket) {
    const int t    = threadIdx.x;
    const int w    = t >> 6;
    const int lane = t & 63;

    if (blockIdx.x < 32) {
        if (blockIdx.x == 0 && t == 0) { *loss_acc = 0.0f; *ticket = 0u; }
        const int r0 = blockIdx.x * 32 + w * 8;
        #pragma unroll
        for (int rr = 0; rr < 8; ++rr) {
            const int r = r0 + rr;
            const f4v v = ((const f4v*)(text + (size_t)r * C_N))[lane];
            float ss = v.x * v.x + v.y * v.y + v.z * v.z + v.w * v.w;
            #pragma unroll
            for (int off = 32; off > 0; off >>= 1) ss += __shfl_xor(ss, off, 64);
            const float inv = 1.0f / fmaxf(sqrtf(ss), 1e-12f);   // matches F.normalize
            ushort4 o;
            o.x = f2bf(v.x * inv); o.y = f2bf(v.y * inv);
            o.z = f2bf(v.z * inv); o.w = f2bf(v.w * inv);
            ((ushort4*)(Bb + (size_t)r * C_N))[lane] = o;
        }
        return;
    }

    const int g = blockIdx.x - 32;                 // 0..16383, 16 channels each
    const size_t ch4 = (size_t)g * 16 + (size_t)w * 4;   // first of this wave's 4 channels
    const f4v* src = (const f4v*)img + ch4 * 144;

    // Issue all 9 loads before any use (independent dests -> deep vmcnt pipe).
    f4v vv[9];
    #pragma unroll
    for (int j = 0; j < 9; ++j)
        vv[j] = __builtin_nontemporal_load(&src[j * 64 + lane]);

    float a0 = 0.f, a1 = 0.f, a2 = 0.f, a3 = 0.f;
    #pragma unroll
    for (int j = 0; j < 9; ++j) {
        const int idx = j * 64 + lane;             // f4 index in [0, 576)
        const float s = (vv[j].x + vv[j].y) + (vv[j].z + vv[j].w);
        // channel boundaries at 144/288/432; 6 of 9 j's fold at compile time
        a0 += (idx < 144)               ? s : 0.0f;
        a1 += (idx >= 144 && idx < 288) ? s : 0.0f;
        a2 += (idx >= 288 && idx < 432) ? s : 0.0f;
        a3 += (idx >= 432)              ? s : 0.0f;
    }

    // 4 interleaved butterflies: independent chains hide bpermute latency.
    #pragma unroll
    for (int off = 32; off > 0; off >>= 1) {
        a0 += __shfl_xor(a0, off, 64);
        a1 += __shfl_xor(a1, off, 64);
        a2 += __shfl_xor(a2, off, 64);
        a3 += __shfl_xor(a3, off, 64);
    }
    if (lane == 0) {
        const float sc = 1.0f / (float)HW_N;
        f4v o; o.x = a0 * sc; o.y = a1 * sc; o.z = a2 * sc; o.w = a3 * sc;
        ((f4v*)pooled)[ch4 >> 2] = o;
    }
}

// ---------------------------------------------------------------------------
// Kernel B: img-row L2-normalize + bf16 cast (text already done in kernel A).
// One wave per row; 256 floats = one float4/lane; butterfly gives every lane
// the norm, all lanes pack + store their ushort4.
// ---------------------------------------------------------------------------
__global__ __launch_bounds__(256) void prep_kernel(const float* __restrict__ pooled,
                                                   unsigned short* __restrict__ Ab) {
    const int w    = threadIdx.x >> 6;
    const int lane = threadIdx.x & 63;
    const int r = blockIdx.x * 4 + w;                       // 0..1023
    const float4 v = ((const float4*)(pooled + (size_t)r * C_N))[lane];
    float ss = v.x * v.x + v.y * v.y + v.z * v.z + v.w * v.w;
    #pragma unroll
    for (int off = 32; off > 0; off >>= 1) ss += __shfl_xor(ss, off, 64);
    const float inv = 1.0f / fmaxf(sqrtf(ss), 1e-12f);
    ushort4 o;
    o.x = f2bf(v.x * inv); o.y = f2bf(v.y * inv);
    o.z = f2bf(v.z * inv); o.w = f2bf(v.w * inv);
    ((ushort4*)(Ab + (size_t)r * C_N))[lane] = o;
}

// ---------------------------------------------------------------------------
// Kernel C: bf16 MFMA GEMM (64x64 tile/block, whole K=256 staged once into
// LDS, XOR-swizzled for conflict-free ds_read_b128 fragment reads) + fused
// BCE-with-logits loss reduction + atomic-ticket finalize.
// Rows are pre-normalized, so logits = acc / TEMP directly; the loss is
// transpose-invariant (labels equality is symmetric).
// ---------------------------------------------------------------------------
__global__ __launch_bounds__(256) void gemm_loss_kernel(const unsigned short* __restrict__ Ab,
                                                        const unsigned short* __restrict__ Bb,
                                                        const int* __restrict__ labels,
                                                        float* __restrict__ loss_acc,
                                                        unsigned int* __restrict__ ticket,
                                                        float* __restrict__ out) {
    __shared__ unsigned short Abuf[64 * 256];   // 32 KB, swizzled
    __shared__ unsigned short Bbuf[64 * 256];   // 32 KB, swizzled

    const int t = threadIdx.x;
    const int rowBase = (blockIdx.x & 15) << 6;
    const int colBase = (blockIdx.x >> 4) << 6;

    // ---- Stage both 64x256 bf16 tiles (one shot, no k-loop). 16B chunks:
    // chunk c -> (row = c>>5, kc = c&31); LDS byte = (row*512+kc*16) ^ ((row&7)<<4).
    #pragma unroll
    for (int i = 0; i < 8; ++i) {
        const int c   = t + (i << 8);           // 0..2047
        const int row = c >> 5;
        const int kc  = c & 31;
        const unsigned off = (unsigned)((row << 9) + (kc << 4)) ^ (unsigned)((row & 7) << 4);
        uint4 va = ((const uint4*)(Ab + (size_t)(rowBase + row) * C_N))[kc];
        *(uint4*)((char*)Abuf + off) = va;
        uint4 vb = ((const uint4*)(Bb + (size_t)(colBase + row) * C_N))[kc];
        *(uint4*)((char*)Bbuf + off) = vb;
    }
    __syncthreads();

    // ---- MFMA: wave w owns rows [w*16, w*16+16) x all 64 cols.
    const int w    = t >> 6;
    const int lane = t & 63;
    const int m16  = lane & 15;
    const int kg   = lane >> 4;

    f32x4 acc[4] = {{0.f, 0.f, 0.f, 0.f}, {0.f, 0.f, 0.f, 0.f},
                    {0.f, 0.f, 0.f, 0.f}, {0.f, 0.f, 0.f, 0.f}};

    #pragma unroll
    for (int s = 0; s < 8; ++s) {               // K = 256 = 8 * 32
        const int kc   = (s << 2) + kg;         // 16B chunk index along k
        const int arow = (w << 4) + m16;
        const bf16x8 a = *(const bf16x8*)((char*)Abuf +
                            (((unsigned)((arow << 9) + (kc << 4))) ^ (unsigned)((arow & 7) << 4)));
        #pragma unroll
        for (int ct = 0; ct < 4; ++ct) {
            const int brow = (ct << 4) + m16;
            const bf16x8 b = *(const bf16x8*)((char*)Bbuf +
                                (((unsigned)((brow << 9) + (kc << 4))) ^ (unsigned)((brow & 7) << 4)));
            acc[ct] = __builtin_amdgcn_mfma_f32_16x16x32_bf16(a, b, acc[ct], 0, 0, 0);
        }
    }

    // ---- Epilogue: logits -> BCE terms -> block reduction -> ticket finalize.
    // D frag: col = lane&15, row = (lane>>4)*4 + reg  [measured m89/m91]
    float lsum = 0.0f;
    const int gi0 = rowBase + (w << 4) + (kg << 2);
    int labi[4];
    #pragma unroll
    for (int r = 0; r < 4; ++r) labi[r] = labels[gi0 + r];
    #pragma unroll
    for (int ct = 0; ct < 4; ++ct) {
        const int gj = colBase + (ct << 4) + m16;
        const int labj = labels[gj];
        #pragma unroll
        for (int r = 0; r < 4; ++r) {
            const float x = acc[ct][r] * TEMP_INV;
            const float z = (labi[r] == labj) ? 1.0f : 0.0f;
            // softplus via fast hw exp/log (v_exp_f32 / v_log_f32 based)
            const float sp = fmaxf(x, 0.0f) + __logf(1.0f + __expf(-fabsf(x)));
            lsum += sp - x * z;
        }
    }

    #pragma unroll
    for (int off = 32; off > 0; off >>= 1) lsum += __shfl_xor(lsum, off, 64);
    __syncthreads();                             // done reading LDS; reuse for reduce
    float* red = (float*)Abuf;
    if ((t & 63) == 0) red[w] = lsum;
    __syncthreads();
    if (t == 0) {
        const float bsum = red[0] + red[1] + red[2] + red[3];
        atomicAdd(loss_acc, bsum);
        __threadfence();
        const unsigned old = atomicAdd(ticket, 1u);
        if (old == 255u) {                       // last of 256 blocks
            const float total = atomicAdd(loss_acc, 0.0f);  // device-scope read
            out[0] = total * (1.0f / ((float)B_N * (float)B_N));
        }
    }
}

extern "C" void kernel_launch(void* const* d_in, const int* in_sizes, int n_in,
                              void* d_out, int out_size, void* d_ws, size_t ws_size,
                              hipStream_t stream) {
    const float* img    = (const float*)d_in[0];   // [1024,256,24,24] fp32
    const float* text   = (const float*)d_in[1];   // [1024,256] fp32
    const int*   labels = (const int*)d_in[2];     // [1024] int32 (JAX demotes int64)
    float* out = (float*)d_out;

    char* ws = (char*)d_ws;
    unsigned short* Ab       = (unsigned short*)ws;                    // 512 KiB bf16
    unsigned short* Bb       = (unsigned short*)(ws + (512 << 10));    // 512 KiB bf16
    float*          pooled   = (float*)(ws + (1 << 20));               // 1 MiB fp32
    float*          loss_acc = (float*)(ws + (2 << 20));               // 4 B
    unsigned int*   ticket   = (unsigned int*)(ws + (2 << 20) + 4);    // 4 B

    pool_kernel<<<32 + 16384, 256, 0, stream>>>(img, text, pooled, Bb, loss_acc, ticket);
    prep_kernel<<<256, 256, 0, stream>>>(pooled, Ab);
    gemm_loss_kernel<<<256, 256, 0, stream>>>(Ab, Bb, labels, loss_acc, ticket, out);
}

// Round 5
// 105.274 us; speedup vs baseline: 1.1349x; 1.0326x over previous
//
#include <hip/hip_runtime.h>
#include <math.h>

// Problem constants (from reference): B=1024, C=256, H=W=24
static constexpr int B_N  = 1024;
static constexpr int C_N  = 256;
static constexpr int HW_N = 576;           // floats per channel = 144 float4
static constexpr float TEMP_INV = 1.0f / 0.07f;

typedef __attribute__((ext_vector_type(8))) short bf16x8;
typedef __attribute__((ext_vector_type(4))) float f32x4;
typedef __attribute__((ext_vector_type(4))) float f4v;

// float -> bf16 round-to-nearest-even (inputs are finite; no NaN handling needed)
static __device__ __forceinline__ unsigned short f2bf(float f) {
    unsigned u = __float_as_uint(f);
    return (unsigned short)((u + 0x7FFFu + ((u >> 16) & 1u)) >> 16);
}

static __device__ __forceinline__ float bf2f(unsigned short h) {
    return __uint_as_float(((unsigned)h) << 16);
}

// ---------------------------------------------------------------------------
// Kernel A: pool + concurrent text normalize. (2-kernel pipeline total.)
//  Blocks 0..31    : text rows (32 rows/block, 8 per wave): fp32 L2-normalize
//                    + bf16 cast -> Bb. Independent of img; rides under the
//                    HBM-bound pooling phase. Block 0 zeroes loss acc/ticket.
//  Blocks 32..16415: pooling. Each wave owns 4 channels = 576 float4.
//                    9 dense nontemporal loads/lane issued before any use
//                    (deep vmcnt pipe), select-accumulate into 4 channel
//                    partials, 4 interleaved butterfly reductions, lane 0
//                    writes the 4 UNNORMALIZED means as bf16 (ushort4) to Ab.
//                    Normalization is deferred to the GEMM epilogue.
// ---------------------------------------------------------------------------
__global__ __launch_bounds__(256) void pool_kernel(const float* __restrict__ img,
                                                   const float* __restrict__ text,
                                                   unsigned short* __restrict__ Ab,
                                                   unsigned short* __restrict__ Bb,
                                                   float* __restrict__ loss_acc,
                                                   unsigned int* __restrict__ ticket) {
    const int t    = threadIdx.x;
    const int w    = t >> 6;
    const int lane = t & 63;

    if (blockIdx.x < 32) {
        if (blockIdx.x == 0 && t == 0) { *loss_acc = 0.0f; *ticket = 0u; }
        const int r0 = blockIdx.x * 32 + w * 8;
        #pragma unroll
        for (int rr = 0; rr < 8; ++rr) {
            const int r = r0 + rr;
            const f4v v = ((const f4v*)(text + (size_t)r * C_N))[lane];
            float ss = v.x * v.x + v.y * v.y + v.z * v.z + v.w * v.w;
            #pragma unroll
            for (int off = 32; off > 0; off >>= 1) ss += __shfl_xor(ss, off, 64);
            const float inv = 1.0f / fmaxf(sqrtf(ss), 1e-12f);   // matches F.normalize
            ushort4 o;
            o.x = f2bf(v.x * inv); o.y = f2bf(v.y * inv);
            o.z = f2bf(v.z * inv); o.w = f2bf(v.w * inv);
            ((ushort4*)(Bb + (size_t)r * C_N))[lane] = o;
        }
        return;
    }

    const int g = blockIdx.x - 32;                 // 0..16383, 16 channels each
    const size_t ch4 = (size_t)g * 16 + (size_t)w * 4;   // first of this wave's 4 channels
    const f4v* src = (const f4v*)img + ch4 * 144;

    // Issue all 9 loads before any use (independent dests -> deep vmcnt pipe).
    f4v vv[9];
    #pragma unroll
    for (int j = 0; j < 9; ++j)
        vv[j] = __builtin_nontemporal_load(&src[j * 64 + lane]);

    float a0 = 0.f, a1 = 0.f, a2 = 0.f, a3 = 0.f;
    #pragma unroll
    for (int j = 0; j < 9; ++j) {
        const int idx = j * 64 + lane;             // f4 index in [0, 576)
        const float s = (vv[j].x + vv[j].y) + (vv[j].z + vv[j].w);
        // channel boundaries at 144/288/432; 6 of 9 j's fold at compile time
        a0 += (idx < 144)               ? s : 0.0f;
        a1 += (idx >= 144 && idx < 288) ? s : 0.0f;
        a2 += (idx >= 288 && idx < 432) ? s : 0.0f;
        a3 += (idx >= 432)              ? s : 0.0f;
    }

    // 4 interleaved butterflies: independent chains hide bpermute latency.
    #pragma unroll
    for (int off = 32; off > 0; off >>= 1) {
        a0 += __shfl_xor(a0, off, 64);
        a1 += __shfl_xor(a1, off, 64);
        a2 += __shfl_xor(a2, off, 64);
        a3 += __shfl_xor(a3, off, 64);
    }
    if (lane == 0) {
        const float sc = 1.0f / (float)HW_N;
        ushort4 o;
        o.x = f2bf(a0 * sc); o.y = f2bf(a1 * sc);
        o.z = f2bf(a2 * sc); o.w = f2bf(a3 * sc);
        ((ushort4*)Ab)[ch4 >> 2] = o;              // Ab[b*256 + c0 .. c0+3]
    }
}

// ---------------------------------------------------------------------------
// Kernel B: bf16 MFMA GEMM (64x64 tile/block, whole K=256 staged once into
// LDS, XOR-swizzled for conflict-free ds_read_b128 fragment reads) + in-kernel
// img-row inverse-norm computation (deferred normalization) + fused
// BCE-with-logits loss reduction + atomic-ticket finalize.
// ---------------------------------------------------------------------------
__global__ __launch_bounds__(256) void gemm_loss_kernel(const unsigned short* __restrict__ Ab,
                                                        const unsigned short* __restrict__ Bb,
                                                        const int* __restrict__ labels,
                                                        float* __restrict__ loss_acc,
                                                        unsigned int* __restrict__ ticket,
                                                        float* __restrict__ out) {
    __shared__ unsigned short Abuf[64 * 256];   // 32 KB, swizzled
    __shared__ unsigned short Bbuf[64 * 256];   // 32 KB, swizzled
    __shared__ float invA[64];

    const int t = threadIdx.x;
    const int rowBase = (blockIdx.x & 15) << 6;
    const int colBase = (blockIdx.x >> 4) << 6;

    // ---- Stage both 64x256 bf16 tiles (one shot, no k-loop). 16B chunks:
    // chunk c -> (row = c>>5, kc = c&31); LDS byte = (row*512+kc*16) ^ ((row&7)<<4).
    #pragma unroll
    for (int i = 0; i < 8; ++i) {
        const int c   = t + (i << 8);           // 0..2047
        const int row = c >> 5;
        const int kc  = c & 31;
        const unsigned off = (unsigned)((row << 9) + (kc << 4)) ^ (unsigned)((row & 7) << 4);
        uint4 va = ((const uint4*)(Ab + (size_t)(rowBase + row) * C_N))[kc];
        *(uint4*)((char*)Abuf + off) = va;
        uint4 vb = ((const uint4*)(Bb + (size_t)(colBase + row) * C_N))[kc];
        *(uint4*)((char*)Bbuf + off) = vb;
    }
    __syncthreads();

    // ---- Deferred normalization: compute inverse L2 norms of the 64 staged
    // (unnormalized) img rows. Thread t -> row t>>2, quarter t&3 (8 chunks).
    {
        const int row = t >> 2;
        const int q   = t & 3;
        float ss = 0.0f;
        #pragma unroll
        for (int j = 0; j < 8; ++j) {
            const int kc = (q << 3) + j;
            const unsigned off = (unsigned)((row << 9) + (kc << 4)) ^ (unsigned)((row & 7) << 4);
            const bf16x8 v = *(const bf16x8*)((char*)Abuf + off);
            #pragma unroll
            for (int e = 0; e < 8; ++e) {
                const float f = bf2f((unsigned short)v[e]);
                ss += f * f;
            }
        }
        ss += __shfl_xor(ss, 1, 64);              // combine the 4 quarter-rows
        ss += __shfl_xor(ss, 2, 64);
        if (q == 0) invA[row] = 1.0f / fmaxf(sqrtf(ss), 1e-12f);
    }
    __syncthreads();

    // ---- MFMA: wave w owns rows [w*16, w*16+16) x all 64 cols.
    const int w    = t >> 6;
    const int lane = t & 63;
    const int m16  = lane & 15;
    const int kg   = lane >> 4;

    f32x4 acc[4] = {{0.f, 0.f, 0.f, 0.f}, {0.f, 0.f, 0.f, 0.f},
                    {0.f, 0.f, 0.f, 0.f}, {0.f, 0.f, 0.f, 0.f}};

    #pragma unroll
    for (int s = 0; s < 8; ++s) {               // K = 256 = 8 * 32
        const int kc   = (s << 2) + kg;         // 16B chunk index along k
        const int arow = (w << 4) + m16;
        const bf16x8 a = *(const bf16x8*)((char*)Abuf +
                            (((unsigned)((arow << 9) + (kc << 4))) ^ (unsigned)((arow & 7) << 4)));
        #pragma unroll
        for (int ct = 0; ct < 4; ++ct) {
            const int brow = (ct << 4) + m16;
            const bf16x8 b = *(const bf16x8*)((char*)Bbuf +
                                (((unsigned)((brow << 9) + (kc << 4))) ^ (unsigned)((brow & 7) << 4)));
            acc[ct] = __builtin_amdgcn_mfma_f32_16x16x32_bf16(a, b, acc[ct], 0, 0, 0);
        }
    }

    // ---- Epilogue: logits -> BCE terms -> block reduction -> ticket finalize.
    // D frag: col = lane&15, row = (lane>>4)*4 + reg  [measured m89/m91]
    float lsum = 0.0f;
    const int lr0 = (w << 4) + (kg << 2);       // local row of acc reg 0
    float sA[4]; int labi[4];
    #pragma unroll
    for (int r = 0; r < 4; ++r) {
        sA[r]   = invA[lr0 + r] * TEMP_INV;
        labi[r] = labels[rowBase + lr0 + r];
    }
    #pragma unroll
    for (int ct = 0; ct < 4; ++ct) {
        const int gj = colBase + (ct << 4) + m16;
        const int labj = labels[gj];
        #pragma unroll
        for (int r = 0; r < 4; ++r) {
            const float x = acc[ct][r] * sA[r];
            const float z = (labi[r] == labj) ? 1.0f : 0.0f;
            // softplus via fast hw exp/log (v_exp_f32 / v_log_f32 based)
            const float sp = fmaxf(x, 0.0f) + __logf(1.0f + __expf(-fabsf(x)));
            lsum += sp - x * z;
        }
    }

    #pragma unroll
    for (int off = 32; off > 0; off >>= 1) lsum += __shfl_xor(lsum, off, 64);
    __syncthreads();                             // done reading LDS; reuse for reduce
    float* red = (float*)Abuf;
    if ((t & 63) == 0) red[w] = lsum;
    __syncthreads();
    if (t == 0) {
        const float bsum = red[0] + red[1] + red[2] + red[3];
        atomicAdd(loss_acc, bsum);
        __threadfence();
        const unsigned old = atomicAdd(ticket, 1u);
        if (old == 255u) {                       // last of 256 blocks
            const float total = atomicAdd(loss_acc, 0.0f);  // device-scope read
            out[0] = total * (1.0f / ((float)B_N * (float)B_N));
        }
    }
}

extern "C" void kernel_launch(void* const* d_in, const int* in_sizes, int n_in,
                              void* d_out, int out_size, void* d_ws, size_t ws_size,
                              hipStream_t stream) {
    const float* img    = (const float*)d_in[0];   // [1024,256,24,24] fp32
    const float* text   = (const float*)d_in[1];   // [1024,256] fp32
    const int*   labels = (const int*)d_in[2];     // [1024] int32 (JAX demotes int64)
    float* out = (float*)d_out;

    char* ws = (char*)d_ws;
    unsigned short* Ab       = (unsigned short*)ws;                    // 512 KiB bf16 (unnormalized means)
    unsigned short* Bb       = (unsigned short*)(ws + (512 << 10));    // 512 KiB bf16 (normalized text)
    float*          loss_acc = (float*)(ws + (1 << 20));               // 4 B
    unsigned int*   ticket   = (unsigned int*)(ws + (1 << 20) + 4);    // 4 B

    pool_kernel<<<32 + 16384, 256, 0, stream>>>(img, text, Ab, Bb, loss_acc, ticket);
    gemm_loss_kernel<<<256, 256, 0, stream>>>(Ab, Bb, labels, loss_acc, ticket, out);
}